// Round 1
// baseline (999.250 us; speedup 1.0000x reference)
//
#include <hip/hip_runtime.h>

// GCN 2-layer forward on MI355X.
// Layer: out[d] = dinv[d] * ( sum_{e: dst[e]=d} hs[src[e]] + hs[d] ) + b
// where hs[i] = (x[i] @ W) * dinv[i]  (self-loop folded into accumulator init).

#define FIN 128
#define F1  64
#define F2  41

// ---- degree -----------------------------------------------------------------
__global__ void k_deg_init(float* __restrict__ deg, int n) {
    int i = blockIdx.x * blockDim.x + threadIdx.x;
    if (i < n) deg[i] = 1.0f;  // self-loop
}

__global__ void k_deg_count(const int* __restrict__ dst, float* __restrict__ deg, int E) {
    int e = blockIdx.x * blockDim.x + threadIdx.x;
    if (e < E) atomicAdd(&deg[dst[e]], 1.0f);
}

__global__ void k_dinv(float* __restrict__ deg, int n) {
    int i = blockIdx.x * blockDim.x + threadIdx.x;
    if (i < n) deg[i] = rsqrtf(deg[i]);  // in-place: deg -> dinv
}

// ---- layer 1 GEMM: hs = (x @ W1) * dinv, also init agg = hs (self-loop) -----
// block = 256 threads = 4 waves; one wave (64 lanes) per node; lane j = out col.
__global__ __launch_bounds__(256) void k_gemm1(
    const float* __restrict__ x, const float* __restrict__ W1,
    const float* __restrict__ dinv, float* __restrict__ hs,
    float* __restrict__ agg, int n) {
    __shared__ float xs[4][FIN];
    int group = threadIdx.x >> 6;
    int lane  = threadIdx.x & 63;
    int node  = blockIdx.x * 4 + group;
    if (node >= n) return;
    // load x row (128 floats) with 64 lanes; wave-internal, no barrier needed
    xs[group][lane]      = x[node * FIN + lane];
    xs[group][lane + 64] = x[node * FIN + 64 + lane];
    float acc = 0.f;
#pragma unroll
    for (int k = 0; k < FIN; k += 4) {
        float4 xv = *(const float4*)&xs[group][k];  // broadcast read
        acc += xv.x * W1[(k + 0) * F1 + lane];
        acc += xv.y * W1[(k + 1) * F1 + lane];
        acc += xv.z * W1[(k + 2) * F1 + lane];
        acc += xv.w * W1[(k + 3) * F1 + lane];
    }
    float v = acc * dinv[node];
    hs[node * F1 + lane]  = v;
    agg[node * F1 + lane] = v;  // self-loop term
}

// ---- scatter layer 1: one wave per edge, lane j = feature ------------------
__global__ __launch_bounds__(256) void k_scatter1(
    const int* __restrict__ src, const int* __restrict__ dst,
    const float* __restrict__ hs, float* __restrict__ agg, int E) {
    int e = blockIdx.x * 4 + (threadIdx.x >> 6);
    if (e >= E) return;
    int lane = threadIdx.x & 63;
    int s = src[e], d = dst[e];
    atomicAdd(&agg[d * F1 + lane], hs[s * F1 + lane]);
}

// ---- finalize layer 1: h1 = relu(agg*dinv + b1) ----------------------------
__global__ void k_fin1(const float* __restrict__ agg, const float* __restrict__ dinv,
                       const float* __restrict__ b1, float* __restrict__ h1, int n) {
    int idx = blockIdx.x * blockDim.x + threadIdx.x;
    if (idx >= n * F1) return;
    int i = idx >> 6, j = idx & 63;
    float v = agg[idx] * dinv[i] + b1[j];
    h1[idx] = v > 0.f ? v : 0.f;
}

// ---- layer 2 GEMM: hs2 = (h1 @ W2) * dinv, agg2 = hs2 ----------------------
__global__ __launch_bounds__(256) void k_gemm2(
    const float* __restrict__ h1, const float* __restrict__ W2,
    const float* __restrict__ dinv, float* __restrict__ hs2,
    float* __restrict__ agg2, int n) {
    __shared__ float hsh[4][F1];
    int group = threadIdx.x >> 6;
    int lane  = threadIdx.x & 63;
    int node  = blockIdx.x * 4 + group;
    if (node >= n) return;
    hsh[group][lane] = h1[node * F1 + lane];
    if (lane < F2) {
        float acc = 0.f;
#pragma unroll
        for (int k = 0; k < F1; k += 4) {
            float4 hv = *(const float4*)&hsh[group][k];
            acc += hv.x * W2[(k + 0) * F2 + lane];
            acc += hv.y * W2[(k + 1) * F2 + lane];
            acc += hv.z * W2[(k + 2) * F2 + lane];
            acc += hv.w * W2[(k + 3) * F2 + lane];
        }
        float v = acc * dinv[node];
        hs2[node * F2 + lane]  = v;
        agg2[node * F2 + lane] = v;  // self-loop
    }
}

// ---- scatter layer 2 -------------------------------------------------------
__global__ __launch_bounds__(256) void k_scatter2(
    const int* __restrict__ src, const int* __restrict__ dst,
    const float* __restrict__ hs2, float* __restrict__ agg2, int E) {
    int e = blockIdx.x * 4 + (threadIdx.x >> 6);
    if (e >= E) return;
    int lane = threadIdx.x & 63;
    if (lane >= F2) return;
    int s = src[e], d = dst[e];
    atomicAdd(&agg2[d * F2 + lane], hs2[s * F2 + lane]);
}

// ---- finalize layer 2: out = agg2*dinv + b2 --------------------------------
__global__ void k_fin2(const float* __restrict__ agg2, const float* __restrict__ dinv,
                       const float* __restrict__ b2, float* __restrict__ out, int n) {
    int idx = blockIdx.x * blockDim.x + threadIdx.x;
    if (idx >= n * F2) return;
    int i = idx / F2, j = idx - i * F2;
    out[idx] = agg2[idx] * dinv[i] + b2[j];
}

extern "C" void kernel_launch(void* const* d_in, const int* in_sizes, int n_in,
                              void* d_out, int out_size, void* d_ws, size_t ws_size,
                              hipStream_t stream) {
    const float* x  = (const float*)d_in[0];
    const int*   ei = (const int*)d_in[1];
    const float* W1 = (const float*)d_in[2];
    const float* b1 = (const float*)d_in[3];
    const float* W2 = (const float*)d_in[4];
    const float* b2 = (const float*)d_in[5];
    float* out = (float*)d_out;

    const int n = in_sizes[0] / FIN;   // 100000
    const int E = in_sizes[1] / 2;     // 1600000
    const int* src = ei;
    const int* dst = ei + E;

    // workspace layout (512B aligned)
    char* ws = (char*)d_ws;
    size_t off = 0;
    auto alloc = [&](size_t bytes) {
        void* p = ws + off;
        off = (off + bytes + 511) & ~(size_t)511;
        return p;
    };
    float* dinv = (float*)alloc((size_t)n * 4);            // deg -> dinv in place
    float* bufA = (float*)alloc((size_t)n * F1 * 4);       // hs1, then h1
    float* bufB = (float*)alloc((size_t)n * F1 * 4);       // agg1, then hs2
    float* bufC = (float*)alloc((size_t)n * F2 * 4);       // agg2

    // degrees
    k_deg_init<<<(n + 255) / 256, 256, 0, stream>>>(dinv, n);
    k_deg_count<<<(E + 255) / 256, 256, 0, stream>>>(dst, dinv, E);
    k_dinv<<<(n + 255) / 256, 256, 0, stream>>>(dinv, n);

    // layer 1
    k_gemm1<<<(n + 3) / 4, 256, 0, stream>>>(x, W1, dinv, bufA, bufB, n);
    k_scatter1<<<(E + 3) / 4, 256, 0, stream>>>(src, dst, bufA, bufB, E);
    k_fin1<<<(n * F1 + 255) / 256, 256, 0, stream>>>(bufB, dinv, b1, bufA, n);

    // layer 2
    k_gemm2<<<(n + 3) / 4, 256, 0, stream>>>(bufA, W2, dinv, bufB, bufC, n);
    k_scatter2<<<(E + 3) / 4, 256, 0, stream>>>(src, dst, bufB, bufC, E);
    k_fin2<<<(n * F2 + 255) / 256, 256, 0, stream>>>(bufC, dinv, b2, out, n);
}

// Round 2
// 574.525 us; speedup vs baseline: 1.7393x; 1.7393x over previous
//
#include <hip/hip_runtime.h>

// GCN 2-layer forward, CSR-gather formulation (no fp32 atomics in hot path).
// out[d] = dinv[d]*( sum_{e:dst=d} hs[src[e]] + hs[d] ) + b,  hs = (x@W)*dinv.
// CSR (rowptr/adj bucketed by dst) built once, reused by both layers.

#define FIN 128
#define F1  64
#define F2  41
#define F2P 48   // padded stride: 48*4=192 B -> rows 64B-aligned, 3 lines/gather

#define SCAN_T 256
#define SCAN_V 4
#define SCAN_B (SCAN_T * SCAN_V)  // 1024 elements per scan block

// ---- CSR build --------------------------------------------------------------
__global__ void k_zero(int* __restrict__ p, int n) {
    int i = blockIdx.x * blockDim.x + threadIdx.x;
    if (i < n) p[i] = 0;
}

__global__ void k_count(const int* __restrict__ dst, int* __restrict__ cnt, int E) {
    int e = blockIdx.x * blockDim.x + threadIdx.x;
    if (e < E) atomicAdd(&cnt[dst[e]], 1);
}

// per-block exclusive scan of cnt (1024 elems/block), emits block totals
__global__ __launch_bounds__(SCAN_T) void k_scan1(
    const int* __restrict__ cnt, int* __restrict__ excl, int* __restrict__ bsum, int n) {
    __shared__ int ts[SCAN_T];
    int t = threadIdx.x, b = blockIdx.x;
    int base = b * SCAN_B + t * SCAN_V;
    int v[SCAN_V]; int s = 0;
#pragma unroll
    for (int j = 0; j < SCAN_V; j++) { int i = base + j; v[j] = (i < n) ? cnt[i] : 0; s += v[j]; }
    ts[t] = s;
    __syncthreads();
    for (int off = 1; off < SCAN_T; off <<= 1) {
        int val = ts[t];
        int add = (t >= off) ? ts[t - off] : 0;
        __syncthreads();
        ts[t] = val + add;
        __syncthreads();
    }
    int incl = ts[t];
    if (t == SCAN_T - 1) bsum[b] = incl;
    int run = incl - s;  // exclusive prefix for this thread
#pragma unroll
    for (int j = 0; j < SCAN_V; j++) { int i = base + j; if (i < n) excl[i] = run; run += v[j]; }
}

// exclusive scan of block totals (nb <= 128), single block of 128
__global__ void k_scan2(int* __restrict__ bsum, int nb) {
    __shared__ int s[128];
    int t = threadIdx.x;
    int v = (t < nb) ? bsum[t] : 0;
    s[t] = v;
    __syncthreads();
    for (int off = 1; off < 128; off <<= 1) {
        int val = s[t];
        int add = (t >= off) ? s[t - off] : 0;
        __syncthreads();
        s[t] = val + add;
        __syncthreads();
    }
    if (t < nb) bsum[t] = s[t] - v;
}

// rowptr = excl + blockoff; fillpos = rowptr; dinv = rsqrt(cnt+1)
__global__ void k_scan3(const int* __restrict__ excl, const int* __restrict__ bsum,
                        const int* __restrict__ cnt, int* __restrict__ rowptr,
                        int* __restrict__ fillpos, float* __restrict__ dinv, int n, int E) {
    int i = blockIdx.x * blockDim.x + threadIdx.x;
    if (i < n) {
        int r = excl[i] + bsum[i / SCAN_B];
        rowptr[i]  = r;
        fillpos[i] = r;
        dinv[i]    = rsqrtf((float)cnt[i] + 1.0f);
    }
    if (i == 0) rowptr[n] = E;
}

__global__ void k_fill(const int* __restrict__ src, const int* __restrict__ dst,
                       int* __restrict__ fillpos, int* __restrict__ adj, int E) {
    int e = blockIdx.x * blockDim.x + threadIdx.x;
    if (e < E) {
        int p = atomicAdd(&fillpos[dst[e]], 1);
        adj[p] = src[e];
    }
}

// ---- layer 1 GEMM: hs = (x @ W1) * dinv ------------------------------------
__global__ __launch_bounds__(256) void k_gemm1(
    const float* __restrict__ x, const float* __restrict__ W1,
    const float* __restrict__ dinv, float* __restrict__ hs, int n) {
    __shared__ float xs[4][FIN];
    int group = threadIdx.x >> 6;
    int lane  = threadIdx.x & 63;
    int node  = blockIdx.x * 4 + group;
    if (node >= n) return;
    xs[group][lane]      = x[node * FIN + lane];
    xs[group][lane + 64] = x[node * FIN + 64 + lane];
    float acc = 0.f;
#pragma unroll
    for (int k = 0; k < FIN; k += 4) {
        float4 xv = *(const float4*)&xs[group][k];  // wave-internal broadcast
        acc += xv.x * W1[(k + 0) * F1 + lane];
        acc += xv.y * W1[(k + 1) * F1 + lane];
        acc += xv.z * W1[(k + 2) * F1 + lane];
        acc += xv.w * W1[(k + 3) * F1 + lane];
    }
    hs[node * F1 + lane] = acc * dinv[node];
}

// ---- layer 1 aggregate + finalize: h1 = relu(dinv*(gather+self) + b1) ------
__global__ __launch_bounds__(256) void k_agg1(
    const int* __restrict__ rowptr, const int* __restrict__ adj,
    const float* __restrict__ hs, const float* __restrict__ dinv,
    const float* __restrict__ b1, float* __restrict__ h1, int n) {
    int node = blockIdx.x * 4 + (threadIdx.x >> 6);
    if (node >= n) return;
    int lane = threadIdx.x & 63;
    int beg = rowptr[node], end = rowptr[node + 1];
    float acc = hs[node * F1 + lane];  // self-loop
    int i = beg;
    for (; i + 4 <= end; i += 4) {
        int s0 = adj[i], s1 = adj[i + 1], s2 = adj[i + 2], s3 = adj[i + 3];
        float a0 = hs[s0 * F1 + lane];
        float a1 = hs[s1 * F1 + lane];
        float a2 = hs[s2 * F1 + lane];
        float a3 = hs[s3 * F1 + lane];
        acc += a0 + a1 + a2 + a3;
    }
    for (; i < end; i++) acc += hs[adj[i] * F1 + lane];
    float v = acc * dinv[node] + b1[lane];
    h1[node * F1 + lane] = v > 0.f ? v : 0.f;
}

// ---- layer 2 GEMM: hs2 = (h1 @ W2) * dinv (stride F2P) ---------------------
__global__ __launch_bounds__(256) void k_gemm2(
    const float* __restrict__ h1, const float* __restrict__ W2,
    const float* __restrict__ dinv, float* __restrict__ hs2, int n) {
    __shared__ float hsh[4][F1];
    int group = threadIdx.x >> 6;
    int lane  = threadIdx.x & 63;
    int node  = blockIdx.x * 4 + group;
    if (node >= n) return;
    hsh[group][lane] = h1[node * F1 + lane];
    if (lane < F2) {
        float acc = 0.f;
#pragma unroll
        for (int k = 0; k < F1; k += 4) {
            float4 hv = *(const float4*)&hsh[group][k];
            acc += hv.x * W2[(k + 0) * F2 + lane];
            acc += hv.y * W2[(k + 1) * F2 + lane];
            acc += hv.z * W2[(k + 2) * F2 + lane];
            acc += hv.w * W2[(k + 3) * F2 + lane];
        }
        hs2[node * F2P + lane] = acc * dinv[node];
    }
}

// ---- layer 2 aggregate + finalize: out = dinv*(gather+self) + b2 -----------
__global__ __launch_bounds__(256) void k_agg2(
    const int* __restrict__ rowptr, const int* __restrict__ adj,
    const float* __restrict__ hs2, const float* __restrict__ dinv,
    const float* __restrict__ b2, float* __restrict__ out, int n) {
    int node = blockIdx.x * 4 + (threadIdx.x >> 6);
    if (node >= n) return;
    int lane = threadIdx.x & 63;
    int beg = rowptr[node], end = rowptr[node + 1];
    float acc = (lane < F2) ? hs2[node * F2P + lane] : 0.f;  // self-loop
    int i = beg;
    for (; i + 4 <= end; i += 4) {
        int s0 = adj[i], s1 = adj[i + 1], s2 = adj[i + 2], s3 = adj[i + 3];
        if (lane < F2) {
            acc += hs2[s0 * F2P + lane];
            acc += hs2[s1 * F2P + lane];
            acc += hs2[s2 * F2P + lane];
            acc += hs2[s3 * F2P + lane];
        }
    }
    for (; i < end; i++)
        if (lane < F2) acc += hs2[adj[i] * F2P + lane];
    if (lane < F2) out[node * F2 + lane] = acc * dinv[node] + b2[lane];
}

extern "C" void kernel_launch(void* const* d_in, const int* in_sizes, int n_in,
                              void* d_out, int out_size, void* d_ws, size_t ws_size,
                              hipStream_t stream) {
    const float* x  = (const float*)d_in[0];
    const int*   ei = (const int*)d_in[1];
    const float* W1 = (const float*)d_in[2];
    const float* b1 = (const float*)d_in[3];
    const float* W2 = (const float*)d_in[4];
    const float* b2 = (const float*)d_in[5];
    float* out = (float*)d_out;

    const int n = in_sizes[0] / FIN;   // 100000
    const int E = in_sizes[1] / 2;     // 1600000
    const int* src = ei;
    const int* dst = ei + E;
    const int nScanBlocks = (n + SCAN_B - 1) / SCAN_B;  // 98 (<=128 required)

    // workspace layout (512B aligned)
    char* ws = (char*)d_ws;
    size_t off = 0;
    auto alloc = [&](size_t bytes) {
        void* p = ws + off;
        off = (off + bytes + 511) & ~(size_t)511;
        return p;
    };
    int*   cnt     = (int*)alloc((size_t)n * 4);
    int*   excl    = (int*)alloc((size_t)n * 4);
    int*   bsum    = (int*)alloc(128 * 4);
    int*   rowptr  = (int*)alloc((size_t)(n + 1) * 4);
    int*   fillpos = (int*)alloc((size_t)n * 4);
    int*   adj     = (int*)alloc((size_t)E * 4);
    float* dinv    = (float*)alloc((size_t)n * 4);
    float* bufHS   = (float*)alloc((size_t)n * F1 * 4);   // hs1, later hs2 (F2P<=F1)
    float* bufH1   = (float*)alloc((size_t)n * F1 * 4);   // h1

    // ---- CSR build (once, reused by both layers) ----
    k_zero<<<(n + 255) / 256, 256, 0, stream>>>(cnt, n);
    k_count<<<(E + 255) / 256, 256, 0, stream>>>(dst, cnt, E);
    k_scan1<<<nScanBlocks, SCAN_T, 0, stream>>>(cnt, excl, bsum, n);
    k_scan2<<<1, 128, 0, stream>>>(bsum, nScanBlocks);
    k_scan3<<<(n + 255) / 256, 256, 0, stream>>>(excl, bsum, cnt, rowptr, fillpos, dinv, n, E);
    k_fill<<<(E + 255) / 256, 256, 0, stream>>>(src, dst, fillpos, adj, E);

    // ---- layer 1 ----
    k_gemm1<<<(n + 3) / 4, 256, 0, stream>>>(x, W1, dinv, bufHS, n);
    k_agg1<<<(n + 3) / 4, 256, 0, stream>>>(rowptr, adj, bufHS, dinv, b1, bufH1, n);

    // ---- layer 2 ----
    k_gemm2<<<(n + 3) / 4, 256, 0, stream>>>(bufH1, W2, dinv, bufHS, n);
    k_agg2<<<(n + 3) / 4, 256, 0, stream>>>(rowptr, adj, bufHS, dinv, b2, out, n);
}

// Round 3
// 422.060 us; speedup vs baseline: 2.3676x; 1.3612x over previous
//
#include <hip/hip_runtime.h>

// GCN 2-layer forward, CSR-gather formulation.
// CSR built via 2-level bucket sort (bucket = dst>>8, 256 nodes/bucket):
//   k_part : bin edges into per-bucket windows (LDS histogram + run-claim)
//   k_build: per-bucket LDS count/scan/place, coalesced stream-out of
//            adj + rowptr + dinv.  No global scatter-fill, no global scan.

#define FIN 128
#define F1  64
#define F2  41
#define F2P 48     // padded stride for hs2 rows (192 B, 64B-aligned)

#define BSH    8                 // bucket = dst >> 8 (256 nodes/bucket)
#define BCAP   6144              // per-bucket edge capacity (mean 4096, >30 sigma)
#define NBMAX  512               // max buckets supported (n <= 131072)
#define CHUNK  4096              // edges per k_part workgroup

// ---- pass 1: bin edges into bucket windows ---------------------------------
__global__ __launch_bounds__(256) void k_part(
    const int* __restrict__ src, const int* __restrict__ dst,
    int* __restrict__ gcur, int* __restrict__ pairs, int E) {
    __shared__ int hist[NBMAX];   // count, then local write cursor
    int tid = threadIdx.x;
    int e0  = blockIdx.x * CHUNK;
    for (int i = tid; i < NBMAX; i += 256) hist[i] = 0;
    __syncthreads();
    // phase A: histogram this chunk's buckets
    for (int j = 0; j < CHUNK / 256; j++) {
        int e = e0 + j * 256 + tid;
        if (e < E) atomicAdd(&hist[dst[e] >> BSH], 1);
    }
    __syncthreads();
    // phase B: claim a contiguous run per bucket, turn hist into cursor
    for (int i = tid; i < NBMAX; i += 256) {
        int c = hist[i];
        hist[i] = c ? atomicAdd(&gcur[i], c) : 0;
    }
    __syncthreads();
    // phase C: re-read edges, place packed (src<<8 | dstLow) into runs
    for (int j = 0; j < CHUNK / 256; j++) {
        int e = e0 + j * 256 + tid;
        if (e < E) {
            int d = dst[e], s = src[e];
            int b = d >> BSH;
            int pos = atomicAdd(&hist[b], 1);
            if (pos < BCAP) pairs[b * BCAP + pos] = (s << BSH) | (d & 255);
        }
    }
}

// ---- exclusive scan of bucket counts (single block of 512) -----------------
__global__ __launch_bounds__(NBMAX) void k_bucketbase(
    const int* __restrict__ gcur, int* __restrict__ bbase,
    int* __restrict__ rowptr, int nbuck, int n, int E) {
    __shared__ int s[NBMAX];
    int t = threadIdx.x;
    int v = (t < nbuck) ? gcur[t] : 0;
    s[t] = v;
    __syncthreads();
    for (int off = 1; off < NBMAX; off <<= 1) {
        int val = s[t];
        int add = (t >= off) ? s[t - off] : 0;
        __syncthreads();
        s[t] = val + add;
        __syncthreads();
    }
    if (t < nbuck) bbase[t] = s[t] - v;   // exclusive
    if (t == 0) rowptr[n] = E;
}

// ---- pass 2: per-bucket CSR build in LDS, coalesced stream-out -------------
__global__ __launch_bounds__(256) void k_build(
    const int* __restrict__ gcur, const int* __restrict__ bbase,
    const int* __restrict__ pairs, int* __restrict__ adj,
    int* __restrict__ rowptr, float* __restrict__ dinv, int n) {
    __shared__ int lcnt[256];     // per-node in-degree (this bucket)
    __shared__ int lex[256];      // exclusive prefix
    __shared__ int lcur[256];     // placement cursor
    __shared__ int ladj[BCAP];    // local adjacency image
    int tid = threadIdx.x;
    int b   = blockIdx.x;
    int base  = bbase[b];
    int cntb  = gcur[b]; if (cntb > BCAP) cntb = BCAP;
    int node0 = b << BSH;
    const int* pb = pairs + (size_t)b * BCAP;

    lcnt[tid] = 0;
    __syncthreads();
    for (int k = tid; k < cntb; k += 256) atomicAdd(&lcnt[pb[k] & 255], 1);
    __syncthreads();
    // Hillis-Steele inclusive scan over 256 counters -> exclusive
    int own = lcnt[tid];
    lex[tid] = own;
    __syncthreads();
    for (int off = 1; off < 256; off <<= 1) {
        int val = lex[tid];
        int add = (tid >= off) ? lex[tid - off] : 0;
        __syncthreads();
        lex[tid] = val + add;
        __syncthreads();
    }
    int excl = lex[tid] - own;
    __syncthreads();
    lex[tid]  = excl;
    lcur[tid] = excl;
    __syncthreads();
    // place srcs into local adj image
    for (int k = tid; k < cntb; k += 256) {
        int pk  = pb[k];
        int pos = atomicAdd(&lcur[pk & 255], 1);
        ladj[pos] = pk >> BSH;
    }
    __syncthreads();
    // coalesced stream-out
    for (int k = tid; k < cntb; k += 256) adj[base + k] = ladj[k];
    int node = node0 + tid;
    if (node < n) {
        rowptr[node] = base + lex[tid];
        dinv[node]   = rsqrtf((float)own + 1.0f);
    }
}

// ---- layer 1 GEMM: hs = (x @ W1) * dinv ------------------------------------
__global__ __launch_bounds__(256) void k_gemm1(
    const float* __restrict__ x, const float* __restrict__ W1,
    const float* __restrict__ dinv, float* __restrict__ hs, int n) {
    __shared__ float xs[4][FIN];
    int group = threadIdx.x >> 6;
    int lane  = threadIdx.x & 63;
    int node  = blockIdx.x * 4 + group;
    if (node >= n) return;
    xs[group][lane]      = x[node * FIN + lane];
    xs[group][lane + 64] = x[node * FIN + 64 + lane];
    float acc = 0.f;
#pragma unroll
    for (int k = 0; k < FIN; k += 4) {
        float4 xv = *(const float4*)&xs[group][k];  // wave-internal broadcast
        acc += xv.x * W1[(k + 0) * F1 + lane];
        acc += xv.y * W1[(k + 1) * F1 + lane];
        acc += xv.z * W1[(k + 2) * F1 + lane];
        acc += xv.w * W1[(k + 3) * F1 + lane];
    }
    hs[node * F1 + lane] = acc * dinv[node];
}

// ---- layer 1 aggregate + finalize: h1 = relu(dinv*(gather+self) + b1) ------
__global__ __launch_bounds__(256) void k_agg1(
    const int* __restrict__ rowptr, const int* __restrict__ adj,
    const float* __restrict__ hs, const float* __restrict__ dinv,
    const float* __restrict__ b1, float* __restrict__ h1, int n) {
    int node = blockIdx.x * 4 + (threadIdx.x >> 6);
    if (node >= n) return;
    int lane = threadIdx.x & 63;
    int beg = rowptr[node], end = rowptr[node + 1];
    float acc = hs[node * F1 + lane];  // self-loop
    int i = beg;
    for (; i + 4 <= end; i += 4) {
        int s0 = adj[i], s1 = adj[i + 1], s2 = adj[i + 2], s3 = adj[i + 3];
        float a0 = hs[s0 * F1 + lane];
        float a1 = hs[s1 * F1 + lane];
        float a2 = hs[s2 * F1 + lane];
        float a3 = hs[s3 * F1 + lane];
        acc += a0 + a1 + a2 + a3;
    }
    for (; i < end; i++) acc += hs[adj[i] * F1 + lane];
    float v = acc * dinv[node] + b1[lane];
    h1[node * F1 + lane] = v > 0.f ? v : 0.f;
}

// ---- layer 2 GEMM: hs2 = (h1 @ W2) * dinv (stride F2P) ---------------------
__global__ __launch_bounds__(256) void k_gemm2(
    const float* __restrict__ h1, const float* __restrict__ W2,
    const float* __restrict__ dinv, float* __restrict__ hs2, int n) {
    __shared__ float hsh[4][F1];
    int group = threadIdx.x >> 6;
    int lane  = threadIdx.x & 63;
    int node  = blockIdx.x * 4 + group;
    if (node >= n) return;
    hsh[group][lane] = h1[node * F1 + lane];
    if (lane < F2) {
        float acc = 0.f;
#pragma unroll
        for (int k = 0; k < F1; k += 4) {
            float4 hv = *(const float4*)&hsh[group][k];
            acc += hv.x * W2[(k + 0) * F2 + lane];
            acc += hv.y * W2[(k + 1) * F2 + lane];
            acc += hv.z * W2[(k + 2) * F2 + lane];
            acc += hv.w * W2[(k + 3) * F2 + lane];
        }
        hs2[node * F2P + lane] = acc * dinv[node];
    }
}

// ---- layer 2 aggregate + finalize: out = dinv*(gather+self) + b2 -----------
__global__ __launch_bounds__(256) void k_agg2(
    const int* __restrict__ rowptr, const int* __restrict__ adj,
    const float* __restrict__ hs2, const float* __restrict__ dinv,
    const float* __restrict__ b2, float* __restrict__ out, int n) {
    int node = blockIdx.x * 4 + (threadIdx.x >> 6);
    if (node >= n) return;
    int lane = threadIdx.x & 63;
    int beg = rowptr[node], end = rowptr[node + 1];
    float acc = (lane < F2) ? hs2[node * F2P + lane] : 0.f;  // self-loop
    int i = beg;
    for (; i + 4 <= end; i += 4) {
        int s0 = adj[i], s1 = adj[i + 1], s2 = adj[i + 2], s3 = adj[i + 3];
        if (lane < F2) {
            acc += hs2[s0 * F2P + lane];
            acc += hs2[s1 * F2P + lane];
            acc += hs2[s2 * F2P + lane];
            acc += hs2[s3 * F2P + lane];
        }
    }
    for (; i < end; i++)
        if (lane < F2) acc += hs2[adj[i] * F2P + lane];
    if (lane < F2) out[node * F2 + lane] = acc * dinv[node] + b2[lane];
}

__global__ void k_zero(int* __restrict__ p, int n) {
    int i = blockIdx.x * blockDim.x + threadIdx.x;
    if (i < n) p[i] = 0;
}

extern "C" void kernel_launch(void* const* d_in, const int* in_sizes, int n_in,
                              void* d_out, int out_size, void* d_ws, size_t ws_size,
                              hipStream_t stream) {
    const float* x  = (const float*)d_in[0];
    const int*   ei = (const int*)d_in[1];
    const float* W1 = (const float*)d_in[2];
    const float* b1 = (const float*)d_in[3];
    const float* W2 = (const float*)d_in[4];
    const float* b2 = (const float*)d_in[5];
    float* out = (float*)d_out;

    const int n = in_sizes[0] / FIN;   // 100000
    const int E = in_sizes[1] / 2;     // 1600000
    const int* src = ei;
    const int* dst = ei + E;
    const int nbuck   = (n + 255) >> BSH;           // 391 (must be <= NBMAX)
    const int nchunks = (E + CHUNK - 1) / CHUNK;    // 391

    // workspace layout (512B aligned)
    char* ws = (char*)d_ws;
    size_t off = 0;
    auto alloc = [&](size_t bytes) {
        void* p = ws + off;
        off = (off + bytes + 511) & ~(size_t)511;
        return p;
    };
    int*   gcur   = (int*)alloc((size_t)NBMAX * 4);
    int*   bbase  = (int*)alloc((size_t)NBMAX * 4);
    int*   pairs  = (int*)alloc((size_t)nbuck * BCAP * 4);   // ~9.6 MB
    int*   adj    = (int*)alloc((size_t)E * 4);
    int*   rowptr = (int*)alloc((size_t)(n + 1) * 4);
    float* dinv   = (float*)alloc((size_t)n * 4);
    float* bufHS  = (float*)alloc((size_t)n * F1 * 4);   // hs1, later hs2 (F2P<=F1)
    float* bufH1  = (float*)alloc((size_t)n * F1 * 4);   // h1

    // ---- CSR build ----
    k_zero<<<(NBMAX + 255) / 256, 256, 0, stream>>>(gcur, NBMAX);
    k_part<<<nchunks, 256, 0, stream>>>(src, dst, gcur, pairs, E);
    k_bucketbase<<<1, NBMAX, 0, stream>>>(gcur, bbase, rowptr, nbuck, n, E);
    k_build<<<nbuck, 256, 0, stream>>>(gcur, bbase, pairs, adj, rowptr, dinv, n);

    // ---- layer 1 ----
    k_gemm1<<<(n + 3) / 4, 256, 0, stream>>>(x, W1, dinv, bufHS, n);
    k_agg1<<<(n + 3) / 4, 256, 0, stream>>>(rowptr, adj, bufHS, dinv, b1, bufH1, n);

    // ---- layer 2 ----
    k_gemm2<<<(n + 3) / 4, 256, 0, stream>>>(bufH1, W2, dinv, bufHS, n);
    k_agg2<<<(n + 3) / 4, 256, 0, stream>>>(rowptr, adj, bufHS, dinv, b2, out, n);
}

// Round 4
// 342.809 us; speedup vs baseline: 2.9149x; 1.2312x over previous
//
#include <hip/hip_runtime.h>

// GCN 2-layer forward, CSR-gather + tiled register-blocked SGEMM.
// CSR built via 2-level bucket sort (bucket = dst>>8):
//   k_part -> k_bucketbase -> k_build  (all writes coalesced or LDS-local)
// GEMMs: 128x64 tile per 256-thread block, 8x4 micro-tile per thread,
//   W resident in LDS, x chunk-staged k-major (transposed) -> FMA-bound.

#define FIN 128
#define F1  64
#define F2  41
#define F2P 48     // padded stride for hs2 rows (192 B, 64B-aligned)

#define BSH    8                 // bucket = dst >> 8 (256 nodes/bucket)
#define BCAP   6144              // per-bucket edge capacity (mean 4096, >30 sigma)
#define NBMAX  512               // max buckets supported (n <= 131072)
#define CHUNK  4096              // edges per k_part workgroup

#define MT 128                   // GEMM M-tile (nodes per block)
#define KC 16                    // GEMM K-chunk

// ---- pass 1: bin edges into bucket windows ---------------------------------
__global__ __launch_bounds__(256) void k_part(
    const int* __restrict__ src, const int* __restrict__ dst,
    int* __restrict__ gcur, int* __restrict__ pairs, int E) {
    __shared__ int hist[NBMAX];   // count, then local write cursor
    int tid = threadIdx.x;
    int e0  = blockIdx.x * CHUNK;
    for (int i = tid; i < NBMAX; i += 256) hist[i] = 0;
    __syncthreads();
    for (int j = 0; j < CHUNK / 256; j++) {
        int e = e0 + j * 256 + tid;
        if (e < E) atomicAdd(&hist[dst[e] >> BSH], 1);
    }
    __syncthreads();
    for (int i = tid; i < NBMAX; i += 256) {
        int c = hist[i];
        hist[i] = c ? atomicAdd(&gcur[i], c) : 0;
    }
    __syncthreads();
    for (int j = 0; j < CHUNK / 256; j++) {
        int e = e0 + j * 256 + tid;
        if (e < E) {
            int d = dst[e], s = src[e];
            int b = d >> BSH;
            int pos = atomicAdd(&hist[b], 1);
            if (pos < BCAP) pairs[b * BCAP + pos] = (s << BSH) | (d & 255);
        }
    }
}

// ---- exclusive scan of bucket counts (single block of 512) -----------------
__global__ __launch_bounds__(NBMAX) void k_bucketbase(
    const int* __restrict__ gcur, int* __restrict__ bbase,
    int* __restrict__ rowptr, int nbuck, int n, int E) {
    __shared__ int s[NBMAX];
    int t = threadIdx.x;
    int v = (t < nbuck) ? gcur[t] : 0;
    s[t] = v;
    __syncthreads();
    for (int off = 1; off < NBMAX; off <<= 1) {
        int val = s[t];
        int add = (t >= off) ? s[t - off] : 0;
        __syncthreads();
        s[t] = val + add;
        __syncthreads();
    }
    if (t < nbuck) bbase[t] = s[t] - v;   // exclusive
    if (t == 0) rowptr[n] = E;
}

// ---- pass 2: per-bucket CSR build in LDS, coalesced stream-out -------------
__global__ __launch_bounds__(256) void k_build(
    const int* __restrict__ gcur, const int* __restrict__ bbase,
    const int* __restrict__ pairs, int* __restrict__ adj,
    int* __restrict__ rowptr, float* __restrict__ dinv, int n) {
    __shared__ int lcnt[256];
    __shared__ int lex[256];
    __shared__ int lcur[256];
    __shared__ int ladj[BCAP];
    int tid = threadIdx.x;
    int b   = blockIdx.x;
    int base  = bbase[b];
    int cntb  = gcur[b]; if (cntb > BCAP) cntb = BCAP;
    int node0 = b << BSH;
    const int* pb = pairs + (size_t)b * BCAP;

    lcnt[tid] = 0;
    __syncthreads();
    for (int k = tid; k < cntb; k += 256) atomicAdd(&lcnt[pb[k] & 255], 1);
    __syncthreads();
    int own = lcnt[tid];
    lex[tid] = own;
    __syncthreads();
    for (int off = 1; off < 256; off <<= 1) {
        int val = lex[tid];
        int add = (tid >= off) ? lex[tid - off] : 0;
        __syncthreads();
        lex[tid] = val + add;
        __syncthreads();
    }
    int excl = lex[tid] - own;
    __syncthreads();
    lex[tid]  = excl;
    lcur[tid] = excl;
    __syncthreads();
    for (int k = tid; k < cntb; k += 256) {
        int pk  = pb[k];
        int pos = atomicAdd(&lcur[pk & 255], 1);
        ladj[pos] = pk >> BSH;
    }
    __syncthreads();
    for (int k = tid; k < cntb; k += 256) adj[base + k] = ladj[k];
    int node = node0 + tid;
    if (node < n) {
        rowptr[node] = base + lex[tid];
        dinv[node]   = rsqrtf((float)own + 1.0f);
    }
}

// ---- layer 1 GEMM (tiled): hs = (x @ W1) * dinv ----------------------------
// 128 nodes x 64 cols per block; W1 (32 KB) resident in LDS; x staged k-major.
__global__ __launch_bounds__(256) void k_mm1(
    const float* __restrict__ x, const float* __restrict__ W1,
    const float* __restrict__ dinv, float* __restrict__ hs, int n) {
    __shared__ float Ws[FIN * F1];   // 32 KB, full W1
    __shared__ float As[KC][MT];     // 8 KB, k-major x chunk
    int t  = threadIdx.x;
    int n0 = blockIdx.x * MT;
    // stage full W1 (coalesced float4, 8 per thread)
#pragma unroll
    for (int j = 0; j < 8; j++) {
        int f = j * 256 + t;
        ((float4*)Ws)[f] = ((const float4*)W1)[f];
    }
    int m0 = (t & 15) * 8;
    int c0 = (t >> 4) * 4;
    int m_l = t & 127;            // staging: node within tile
    int kh  = (t >> 7) * 8;       // staging: k-subchunk (0 or 8)
    bool mvalid = (n0 + m_l) < n;
    const float* xrow = x + (size_t)(n0 + m_l) * FIN + kh;
    float acc[8][4] = {};
    for (int kc = 0; kc < FIN; kc += KC) {
        __syncthreads();
        float4 v0 = mvalid ? *(const float4*)(xrow + kc)     : float4{0.f,0.f,0.f,0.f};
        float4 v1 = mvalid ? *(const float4*)(xrow + kc + 4) : float4{0.f,0.f,0.f,0.f};
        As[kh + 0][m_l] = v0.x; As[kh + 1][m_l] = v0.y;
        As[kh + 2][m_l] = v0.z; As[kh + 3][m_l] = v0.w;
        As[kh + 4][m_l] = v1.x; As[kh + 5][m_l] = v1.y;
        As[kh + 6][m_l] = v1.z; As[kh + 7][m_l] = v1.w;
        __syncthreads();
#pragma unroll
        for (int k = 0; k < KC; k++) {
            float4 a0 = *(const float4*)&As[k][m0];
            float4 a1 = *(const float4*)&As[k][m0 + 4];
            float4 w  = *(const float4*)&Ws[(kc + k) * F1 + c0];
            float a[8] = {a0.x, a0.y, a0.z, a0.w, a1.x, a1.y, a1.z, a1.w};
#pragma unroll
            for (int i = 0; i < 8; i++) {
                acc[i][0] += a[i] * w.x;
                acc[i][1] += a[i] * w.y;
                acc[i][2] += a[i] * w.z;
                acc[i][3] += a[i] * w.w;
            }
        }
    }
#pragma unroll
    for (int i = 0; i < 8; i++) {
        int node = n0 + m0 + i;
        if (node < n) {
            float dv = dinv[node];
            float4 o = {acc[i][0] * dv, acc[i][1] * dv, acc[i][2] * dv, acc[i][3] * dv};
            *(float4*)&hs[(size_t)node * F1 + c0] = o;
        }
    }
}

// ---- layer 2 GEMM (tiled): hs2 = (h1 @ W2) * dinv, N padded 41->48 ---------
// pad W cols are 0 -> pad outputs are 0 (stored, unread by k_agg2).
__global__ __launch_bounds__(256) void k_mm2(
    const float* __restrict__ h1, const float* __restrict__ W2,
    const float* __restrict__ dinv, float* __restrict__ hs2, int n) {
    __shared__ float Ws[F1 * F2P];   // 12 KB padded
    __shared__ float As[KC][MT];
    int t  = threadIdx.x;
    int n0 = blockIdx.x * MT;
    for (int idx = t; idx < F1 * F2P; idx += 256) {
        int k = idx / F2P, c = idx - k * F2P;
        Ws[idx] = (c < F2) ? W2[k * F2 + c] : 0.f;
    }
    int m0 = (t & 15) * 8;           // only meaningful for t < 192
    int c0 = (t >> 4) * 4;           // 0..60; compute only if c0 < 48
    bool compute = (t < 192);        // waves 0-2 compute, wave 3 stages only
    int m_l = t & 127;
    int kh  = (t >> 7) * 8;
    bool mvalid = (n0 + m_l) < n;
    const float* hrow = h1 + (size_t)(n0 + m_l) * F1 + kh;
    float acc[8][4] = {};
    for (int kc = 0; kc < F1; kc += KC) {
        __syncthreads();
        float4 v0 = mvalid ? *(const float4*)(hrow + kc)     : float4{0.f,0.f,0.f,0.f};
        float4 v1 = mvalid ? *(const float4*)(hrow + kc + 4) : float4{0.f,0.f,0.f,0.f};
        As[kh + 0][m_l] = v0.x; As[kh + 1][m_l] = v0.y;
        As[kh + 2][m_l] = v0.z; As[kh + 3][m_l] = v0.w;
        As[kh + 4][m_l] = v1.x; As[kh + 5][m_l] = v1.y;
        As[kh + 6][m_l] = v1.z; As[kh + 7][m_l] = v1.w;
        __syncthreads();
        if (compute) {
#pragma unroll
            for (int k = 0; k < KC; k++) {
                float4 a0 = *(const float4*)&As[k][m0];
                float4 a1 = *(const float4*)&As[k][m0 + 4];
                float4 w  = *(const float4*)&Ws[(kc + k) * F2P + c0];
                float a[8] = {a0.x, a0.y, a0.z, a0.w, a1.x, a1.y, a1.z, a1.w};
#pragma unroll
                for (int i = 0; i < 8; i++) {
                    acc[i][0] += a[i] * w.x;
                    acc[i][1] += a[i] * w.y;
                    acc[i][2] += a[i] * w.z;
                    acc[i][3] += a[i] * w.w;
                }
            }
        }
    }
    if (compute) {
#pragma unroll
        for (int i = 0; i < 8; i++) {
            int node = n0 + m0 + i;
            if (node < n) {
                float dv = dinv[node];
                float4 o = {acc[i][0] * dv, acc[i][1] * dv, acc[i][2] * dv, acc[i][3] * dv};
                *(float4*)&hs2[(size_t)node * F2P + c0] = o;
            }
        }
    }
}

// ---- layer 1 aggregate + finalize: h1 = relu(dinv*(gather+self) + b1) ------
__global__ __launch_bounds__(256) void k_agg1(
    const int* __restrict__ rowptr, const int* __restrict__ adj,
    const float* __restrict__ hs, const float* __restrict__ dinv,
    const float* __restrict__ b1, float* __restrict__ h1, int n) {
    int node = blockIdx.x * 4 + (threadIdx.x >> 6);
    if (node >= n) return;
    int lane = threadIdx.x & 63;
    int beg = rowptr[node], end = rowptr[node + 1];
    float acc = hs[node * F1 + lane];  // self-loop
    int i = beg;
    for (; i + 4 <= end; i += 4) {
        int s0 = adj[i], s1 = adj[i + 1], s2 = adj[i + 2], s3 = adj[i + 3];
        float a0 = hs[s0 * F1 + lane];
        float a1 = hs[s1 * F1 + lane];
        float a2 = hs[s2 * F1 + lane];
        float a3 = hs[s3 * F1 + lane];
        acc += a0 + a1 + a2 + a3;
    }
    for (; i < end; i++) acc += hs[adj[i] * F1 + lane];
    float v = acc * dinv[node] + b1[lane];
    h1[node * F1 + lane] = v > 0.f ? v : 0.f;
}

// ---- layer 2 aggregate + finalize: out = dinv*(gather+self) + b2 -----------
__global__ __launch_bounds__(256) void k_agg2(
    const int* __restrict__ rowptr, const int* __restrict__ adj,
    const float* __restrict__ hs2, const float* __restrict__ dinv,
    const float* __restrict__ b2, float* __restrict__ out, int n) {
    int node = blockIdx.x * 4 + (threadIdx.x >> 6);
    if (node >= n) return;
    int lane = threadIdx.x & 63;
    int beg = rowptr[node], end = rowptr[node + 1];
    float acc = (lane < F2) ? hs2[node * F2P + lane] : 0.f;  // self-loop
    int i = beg;
    for (; i + 4 <= end; i += 4) {
        int s0 = adj[i], s1 = adj[i + 1], s2 = adj[i + 2], s3 = adj[i + 3];
        if (lane < F2) {
            acc += hs2[s0 * F2P + lane];
            acc += hs2[s1 * F2P + lane];
            acc += hs2[s2 * F2P + lane];
            acc += hs2[s3 * F2P + lane];
        }
    }
    for (; i < end; i++)
        if (lane < F2) acc += hs2[adj[i] * F2P + lane];
    if (lane < F2) out[node * F2 + lane] = acc * dinv[node] + b2[lane];
}

__global__ void k_zero(int* __restrict__ p, int n) {
    int i = blockIdx.x * blockDim.x + threadIdx.x;
    if (i < n) p[i] = 0;
}

extern "C" void kernel_launch(void* const* d_in, const int* in_sizes, int n_in,
                              void* d_out, int out_size, void* d_ws, size_t ws_size,
                              hipStream_t stream) {
    const float* x  = (const float*)d_in[0];
    const int*   ei = (const int*)d_in[1];
    const float* W1 = (const float*)d_in[2];
    const float* b1 = (const float*)d_in[3];
    const float* W2 = (const float*)d_in[4];
    const float* b2 = (const float*)d_in[5];
    float* out = (float*)d_out;

    const int n = in_sizes[0] / FIN;   // 100000
    const int E = in_sizes[1] / 2;     // 1600000
    const int* src = ei;
    const int* dst = ei + E;
    const int nbuck   = (n + 255) >> BSH;           // 391 (<= NBMAX)
    const int nchunks = (E + CHUNK - 1) / CHUNK;    // 391
    const int nmm     = (n + MT - 1) / MT;          // 782

    // workspace layout (512B aligned)
    char* ws = (char*)d_ws;
    size_t off = 0;
    auto alloc = [&](size_t bytes) {
        void* p = ws + off;
        off = (off + bytes + 511) & ~(size_t)511;
        return p;
    };
    int*   gcur   = (int*)alloc((size_t)NBMAX * 4);
    int*   bbase  = (int*)alloc((size_t)NBMAX * 4);
    int*   pairs  = (int*)alloc((size_t)nbuck * BCAP * 4);   // ~9.6 MB
    int*   adj    = (int*)alloc((size_t)E * 4);
    int*   rowptr = (int*)alloc((size_t)(n + 1) * 4);
    float* dinv   = (float*)alloc((size_t)n * 4);
    float* bufHS  = (float*)alloc((size_t)n * F1 * 4);   // hs1, later hs2 (F2P<=F1)
    float* bufH1  = (float*)alloc((size_t)n * F1 * 4);   // h1

    // ---- CSR build ----
    k_zero<<<(NBMAX + 255) / 256, 256, 0, stream>>>(gcur, NBMAX);
    k_part<<<nchunks, 256, 0, stream>>>(src, dst, gcur, pairs, E);
    k_bucketbase<<<1, NBMAX, 0, stream>>>(gcur, bbase, rowptr, nbuck, n, E);
    k_build<<<nbuck, 256, 0, stream>>>(gcur, bbase, pairs, adj, rowptr, dinv, n);

    // ---- layer 1 ----
    k_mm1<<<nmm, 256, 0, stream>>>(x, W1, dinv, bufHS, n);
    k_agg1<<<(n + 3) / 4, 256, 0, stream>>>(rowptr, adj, bufHS, dinv, b1, bufH1, n);

    // ---- layer 2 ----
    k_mm2<<<nmm, 256, 0, stream>>>(bufH1, W2, dinv, bufHS, n);
    k_agg2<<<(n + 3) / 4, 256, 0, stream>>>(rowptr, adj, bufHS, dinv, b2, out, n);
}

// Round 5
// 321.978 us; speedup vs baseline: 3.1035x; 1.0647x over previous
//
#include <hip/hip_runtime.h>

// GCN 2-layer forward, CSR-gather + tiled SGEMM + bf16 gather payloads.
// CSR built via 2-level bucket sort (bucket = dst>>8).
// GEMMs: 128x64 tile/block, 8x4 micro-tile/thread, W in LDS, fp32.
// Aggregation: gather bf16 rows (fp32 accumulate) -> halves random-line traffic.

#define FIN 128
#define F1  64
#define F2  41
#define F2P 48     // hs2 bf16 row stride: 48*2=96 B (payload 82 B, always 2 lines)

#define BSH    8                 // bucket = dst >> 8 (256 nodes/bucket)
#define BCAP   6144              // per-bucket edge capacity (mean 4096, >30 sigma)
#define NBMAX  512               // max buckets supported (n <= 131072)
#define CHUNK  4096              // edges per k_part workgroup (16/thread)

#define MT 128                   // GEMM M-tile
#define KC 16                    // GEMM K-chunk

__device__ __forceinline__ unsigned short f2bf(float f) {
    unsigned u = __builtin_bit_cast(unsigned, f);
    u += 0x7FFFu + ((u >> 16) & 1u);           // round-to-nearest-even
    return (unsigned short)(u >> 16);
}
__device__ __forceinline__ float bf2f(unsigned short h) {
    unsigned u = ((unsigned)h) << 16;
    return __builtin_bit_cast(float, u);
}

// ---- pass 1: bin edges into bucket windows (edges cached in registers) -----
__global__ __launch_bounds__(256) void k_part(
    const int* __restrict__ src, const int* __restrict__ dst,
    int* __restrict__ gcur, int* __restrict__ pairs, int E) {
    __shared__ int hist[NBMAX];
    int tid = threadIdx.x;
    int e0  = blockIdx.x * CHUNK;
    int ds[CHUNK / 256], ss[CHUNK / 256];
#pragma unroll
    for (int j = 0; j < CHUNK / 256; j++) {
        int e = e0 + j * 256 + tid;
        if (e < E) { ds[j] = dst[e]; ss[j] = src[e]; } else ds[j] = -1;
    }
    for (int i = tid; i < NBMAX; i += 256) hist[i] = 0;
    __syncthreads();
#pragma unroll
    for (int j = 0; j < CHUNK / 256; j++)
        if (ds[j] >= 0) atomicAdd(&hist[ds[j] >> BSH], 1);
    __syncthreads();
    for (int i = tid; i < NBMAX; i += 256) {
        int c = hist[i];
        hist[i] = c ? atomicAdd(&gcur[i], c) : 0;
    }
    __syncthreads();
#pragma unroll
    for (int j = 0; j < CHUNK / 256; j++) {
        if (ds[j] >= 0) {
            int b = ds[j] >> BSH;
            int pos = atomicAdd(&hist[b], 1);
            if (pos < BCAP) pairs[b * BCAP + pos] = (ss[j] << BSH) | (ds[j] & 255);
        }
    }
}

// ---- exclusive scan of bucket counts ---------------------------------------
__global__ __launch_bounds__(NBMAX) void k_bucketbase(
    const int* __restrict__ gcur, int* __restrict__ bbase,
    int* __restrict__ rowptr, int nbuck, int n, int E) {
    __shared__ int s[NBMAX];
    int t = threadIdx.x;
    int v = (t < nbuck) ? gcur[t] : 0;
    s[t] = v;
    __syncthreads();
    for (int off = 1; off < NBMAX; off <<= 1) {
        int val = s[t];
        int add = (t >= off) ? s[t - off] : 0;
        __syncthreads();
        s[t] = val + add;
        __syncthreads();
    }
    if (t < nbuck) bbase[t] = s[t] - v;
    if (t == 0) rowptr[n] = E;
}

// ---- pass 2: per-bucket CSR build in LDS, coalesced stream-out -------------
__global__ __launch_bounds__(256) void k_build(
    const int* __restrict__ gcur, const int* __restrict__ bbase,
    const int* __restrict__ pairs, int* __restrict__ adj,
    int* __restrict__ rowptr, float* __restrict__ dinv, int n) {
    __shared__ int lcnt[256];
    __shared__ int lex[256];
    __shared__ int lcur[256];
    __shared__ int ladj[BCAP];
    int tid = threadIdx.x;
    int b   = blockIdx.x;
    int base  = bbase[b];
    int cntb  = gcur[b]; if (cntb > BCAP) cntb = BCAP;
    int node0 = b << BSH;
    const int* pb = pairs + (size_t)b * BCAP;

    lcnt[tid] = 0;
    __syncthreads();
    for (int k = tid; k < cntb; k += 256) atomicAdd(&lcnt[pb[k] & 255], 1);
    __syncthreads();
    int own = lcnt[tid];
    lex[tid] = own;
    __syncthreads();
    for (int off = 1; off < 256; off <<= 1) {
        int val = lex[tid];
        int add = (tid >= off) ? lex[tid - off] : 0;
        __syncthreads();
        lex[tid] = val + add;
        __syncthreads();
    }
    int excl = lex[tid] - own;
    __syncthreads();
    lex[tid]  = excl;
    lcur[tid] = excl;
    __syncthreads();
    for (int k = tid; k < cntb; k += 256) {
        int pk  = pb[k];
        int pos = atomicAdd(&lcur[pk & 255], 1);
        ladj[pos] = pk >> BSH;
    }
    __syncthreads();
    for (int k = tid; k < cntb; k += 256) adj[base + k] = ladj[k];
    int node = node0 + tid;
    if (node < n) {
        rowptr[node] = base + lex[tid];
        dinv[node]   = rsqrtf((float)own + 1.0f);
    }
}

// ---- layer 1 GEMM (tiled): hs1 = bf16( (x @ W1) * dinv ) -------------------
__global__ __launch_bounds__(256) void k_mm1(
    const float* __restrict__ x, const float* __restrict__ W1,
    const float* __restrict__ dinv, unsigned short* __restrict__ hs, int n) {
    __shared__ float Ws[FIN * F1];   // 32 KB
    __shared__ float As[KC][MT];     // 8 KB
    int t  = threadIdx.x;
    int n0 = blockIdx.x * MT;
#pragma unroll
    for (int j = 0; j < 8; j++) {
        int f = j * 256 + t;
        ((float4*)Ws)[f] = ((const float4*)W1)[f];
    }
    int m0 = (t & 15) * 8;
    int c0 = (t >> 4) * 4;
    int m_l = t & 127;
    int kh  = (t >> 7) * 8;
    bool mvalid = (n0 + m_l) < n;
    const float* xrow = x + (size_t)(n0 + m_l) * FIN + kh;
    float acc[8][4] = {};
    for (int kc = 0; kc < FIN; kc += KC) {
        __syncthreads();
        float4 v0 = mvalid ? *(const float4*)(xrow + kc)     : float4{0.f,0.f,0.f,0.f};
        float4 v1 = mvalid ? *(const float4*)(xrow + kc + 4) : float4{0.f,0.f,0.f,0.f};
        As[kh + 0][m_l] = v0.x; As[kh + 1][m_l] = v0.y;
        As[kh + 2][m_l] = v0.z; As[kh + 3][m_l] = v0.w;
        As[kh + 4][m_l] = v1.x; As[kh + 5][m_l] = v1.y;
        As[kh + 6][m_l] = v1.z; As[kh + 7][m_l] = v1.w;
        __syncthreads();
#pragma unroll
        for (int k = 0; k < KC; k++) {
            float4 a0 = *(const float4*)&As[k][m0];
            float4 a1 = *(const float4*)&As[k][m0 + 4];
            float4 w  = *(const float4*)&Ws[(kc + k) * F1 + c0];
            float a[8] = {a0.x, a0.y, a0.z, a0.w, a1.x, a1.y, a1.z, a1.w};
#pragma unroll
            for (int i = 0; i < 8; i++) {
                acc[i][0] += a[i] * w.x;
                acc[i][1] += a[i] * w.y;
                acc[i][2] += a[i] * w.z;
                acc[i][3] += a[i] * w.w;
            }
        }
    }
#pragma unroll
    for (int i = 0; i < 8; i++) {
        int node = n0 + m0 + i;
        if (node < n) {
            float dv = dinv[node];
            ushort4 o = { f2bf(acc[i][0] * dv), f2bf(acc[i][1] * dv),
                          f2bf(acc[i][2] * dv), f2bf(acc[i][3] * dv) };
            *(ushort4*)&hs[(size_t)node * F1 + c0] = o;
        }
    }
}

// ---- layer 1 aggregate: h1 = relu(dinv*(gather+self) + b1), fp32 out -------
__global__ __launch_bounds__(256) void k_agg1(
    const int* __restrict__ rowptr, const int* __restrict__ adj,
    const unsigned short* __restrict__ hs, const float* __restrict__ dinv,
    const float* __restrict__ b1, float* __restrict__ h1, int n) {
    int node = blockIdx.x * 4 + (threadIdx.x >> 6);
    if (node >= n) return;
    int lane = threadIdx.x & 63;
    int beg = rowptr[node], end = rowptr[node + 1];
    float acc = bf2f(hs[(size_t)node * F1 + lane]);  // self-loop
    int i = beg;
    for (; i + 4 <= end; i += 4) {
        int s0 = adj[i], s1 = adj[i + 1], s2 = adj[i + 2], s3 = adj[i + 3];
        float a0 = bf2f(hs[(size_t)s0 * F1 + lane]);
        float a1 = bf2f(hs[(size_t)s1 * F1 + lane]);
        float a2 = bf2f(hs[(size_t)s2 * F1 + lane]);
        float a3 = bf2f(hs[(size_t)s3 * F1 + lane]);
        acc += a0 + a1 + a2 + a3;
    }
    for (; i < end; i++) acc += bf2f(hs[(size_t)adj[i] * F1 + lane]);
    float v = acc * dinv[node] + b1[lane];
    h1[(size_t)node * F1 + lane] = v > 0.f ? v : 0.f;
}

// ---- layer 2 GEMM (tiled): hs2 = bf16( (h1 @ W2) * dinv ), stride F2P ------
__global__ __launch_bounds__(256) void k_mm2(
    const float* __restrict__ h1, const float* __restrict__ W2,
    const float* __restrict__ dinv, unsigned short* __restrict__ hs2, int n) {
    __shared__ float Ws[F1 * F2P];   // 12 KB padded (cols 41..47 = 0)
    __shared__ float As[KC][MT];
    int t  = threadIdx.x;
    int n0 = blockIdx.x * MT;
    for (int idx = t; idx < F1 * F2P; idx += 256) {
        int k = idx / F2P, c = idx - k * F2P;
        Ws[idx] = (c < F2) ? W2[k * F2 + c] : 0.f;
    }
    int m0 = (t & 15) * 8;
    int c0 = (t >> 4) * 4;
    bool compute = (t < 192);        // waves 0-2 compute (48 cols), wave 3 stages
    int m_l = t & 127;
    int kh  = (t >> 7) * 8;
    bool mvalid = (n0 + m_l) < n;
    const float* hrow = h1 + (size_t)(n0 + m_l) * F1 + kh;
    float acc[8][4] = {};
    for (int kc = 0; kc < F1; kc += KC) {
        __syncthreads();
        float4 v0 = mvalid ? *(const float4*)(hrow + kc)     : float4{0.f,0.f,0.f,0.f};
        float4 v1 = mvalid ? *(const float4*)(hrow + kc + 4) : float4{0.f,0.f,0.f,0.f};
        As[kh + 0][m_l] = v0.x; As[kh + 1][m_l] = v0.y;
        As[kh + 2][m_l] = v0.z; As[kh + 3][m_l] = v0.w;
        As[kh + 4][m_l] = v1.x; As[kh + 5][m_l] = v1.y;
        As[kh + 6][m_l] = v1.z; As[kh + 7][m_l] = v1.w;
        __syncthreads();
        if (compute) {
#pragma unroll
            for (int k = 0; k < KC; k++) {
                float4 a0 = *(const float4*)&As[k][m0];
                float4 a1 = *(const float4*)&As[k][m0 + 4];
                float4 w  = *(const float4*)&Ws[(kc + k) * F2P + c0];
                float a[8] = {a0.x, a0.y, a0.z, a0.w, a1.x, a1.y, a1.z, a1.w};
#pragma unroll
                for (int i = 0; i < 8; i++) {
                    acc[i][0] += a[i] * w.x;
                    acc[i][1] += a[i] * w.y;
                    acc[i][2] += a[i] * w.z;
                    acc[i][3] += a[i] * w.w;
                }
            }
        }
    }
    if (compute) {
#pragma unroll
        for (int i = 0; i < 8; i++) {
            int node = n0 + m0 + i;
            if (node < n) {
                float dv = dinv[node];
                ushort4 o = { f2bf(acc[i][0] * dv), f2bf(acc[i][1] * dv),
                              f2bf(acc[i][2] * dv), f2bf(acc[i][3] * dv) };
                *(ushort4*)&hs2[(size_t)node * F2P + c0] = o;  // 96n+2c0, 8B-aligned
            }
        }
    }
}

// ---- layer 2 aggregate: out = dinv*(gather+self) + b2, fp32 out ------------
__global__ __launch_bounds__(256) void k_agg2(
    const int* __restrict__ rowptr, const int* __restrict__ adj,
    const unsigned short* __restrict__ hs2, const float* __restrict__ dinv,
    const float* __restrict__ b2, float* __restrict__ out, int n) {
    int node = blockIdx.x * 4 + (threadIdx.x >> 6);
    if (node >= n) return;
    int lane = threadIdx.x & 63;
    int beg = rowptr[node], end = rowptr[node + 1];
    float acc = (lane < F2) ? bf2f(hs2[(size_t)node * F2P + lane]) : 0.f;
    int i = beg;
    for (; i + 4 <= end; i += 4) {
        int s0 = adj[i], s1 = adj[i + 1], s2 = adj[i + 2], s3 = adj[i + 3];
        if (lane < F2) {
            acc += bf2f(hs2[(size_t)s0 * F2P + lane]);
            acc += bf2f(hs2[(size_t)s1 * F2P + lane]);
            acc += bf2f(hs2[(size_t)s2 * F2P + lane]);
            acc += bf2f(hs2[(size_t)s3 * F2P + lane]);
        }
    }
    for (; i < end; i++)
        if (lane < F2) acc += bf2f(hs2[(size_t)adj[i] * F2P + lane]);
    if (lane < F2) out[(size_t)node * F2 + lane] = acc * dinv[node] + b2[lane];
}

__global__ void k_zero(int* __restrict__ p, int n) {
    int i = blockIdx.x * blockDim.x + threadIdx.x;
    if (i < n) p[i] = 0;
}

extern "C" void kernel_launch(void* const* d_in, const int* in_sizes, int n_in,
                              void* d_out, int out_size, void* d_ws, size_t ws_size,
                              hipStream_t stream) {
    const float* x  = (const float*)d_in[0];
    const int*   ei = (const int*)d_in[1];
    const float* W1 = (const float*)d_in[2];
    const float* b1 = (const float*)d_in[3];
    const float* W2 = (const float*)d_in[4];
    const float* b2 = (const float*)d_in[5];
    float* out = (float*)d_out;

    const int n = in_sizes[0] / FIN;   // 100000
    const int E = in_sizes[1] / 2;     // 1600000
    const int* src = ei;
    const int* dst = ei + E;
    const int nbuck   = (n + 255) >> BSH;           // 391 (<= NBMAX)
    const int nchunks = (E + CHUNK - 1) / CHUNK;    // 391
    const int nmm     = (n + MT - 1) / MT;          // 782

    char* ws = (char*)d_ws;
    size_t off = 0;
    auto alloc = [&](size_t bytes) {
        void* p = ws + off;
        off = (off + bytes + 511) & ~(size_t)511;
        return p;
    };
    int*   gcur   = (int*)alloc((size_t)NBMAX * 4);
    int*   bbase  = (int*)alloc((size_t)NBMAX * 4);
    int*   pairs  = (int*)alloc((size_t)nbuck * BCAP * 4);   // ~9.6 MB
    int*   adj    = (int*)alloc((size_t)E * 4);
    int*   rowptr = (int*)alloc((size_t)(n + 1) * 4);
    float* dinv   = (float*)alloc((size_t)n * 4);
    unsigned short* bufHS = (unsigned short*)alloc((size_t)n * F1 * 2); // hs1 bf16; later hs2 (F2P<F1)
    float* bufH1  = (float*)alloc((size_t)n * F1 * 4);   // h1 fp32

    // ---- CSR build ----
    k_zero<<<(NBMAX + 255) / 256, 256, 0, stream>>>(gcur, NBMAX);
    k_part<<<nchunks, 256, 0, stream>>>(src, dst, gcur, pairs, E);
    k_bucketbase<<<1, NBMAX, 0, stream>>>(gcur, bbase, rowptr, nbuck, n, E);
    k_build<<<nbuck, 256, 0, stream>>>(gcur, bbase, pairs, adj, rowptr, dinv, n);

    // ---- layer 1 ----
    k_mm1<<<nmm, 256, 0, stream>>>(x, W1, dinv, bufHS, n);
    k_agg1<<<(n + 3) / 4, 256, 0, stream>>>(rowptr, adj, bufHS, dinv, b1, bufH1, n);

    // ---- layer 2 ----
    k_mm2<<<nmm, 256, 0, stream>>>(bufH1, W2, dinv, bufHS, n);
    k_agg2<<<(n + 3) / 4, 256, 0, stream>>>(rowptr, adj, bufHS, dinv, b2, out, n);
}

// Round 6
// 295.711 us; speedup vs baseline: 3.3791x; 1.0888x over previous
//
#include <hip/hip_runtime.h>

// GCN 2-layer forward, CSR-gather + tiled SGEMM + bf16 gather payloads.
// CSR built via 2-level bucket sort (bucket = dst>>8).
// Aggregation: per-node wave, adjacency batch-loaded coalesced (1 VMEM/64
// edges) + __shfl broadcast -> 8 independent gathers in flight (MLP-rich,
// no adj->gather chain).

#define FIN 128
#define F1  64
#define F2  41
#define F2P 48     // hs2 bf16 row stride: 48*2=96 B (payload 82 B, 2 lines)

#define BSH    8                 // bucket = dst >> 8 (256 nodes/bucket)
#define BCAP   6144              // per-bucket edge capacity (mean 4096, >30 sigma)
#define NBMAX  512               // max buckets supported (n <= 131072)
#define CHUNK  4096              // edges per k_part workgroup (16/thread)

#define MT 128                   // GEMM M-tile
#define KC 16                    // GEMM K-chunk

__device__ __forceinline__ unsigned short f2bf(float f) {
    unsigned u = __builtin_bit_cast(unsigned, f);
    u += 0x7FFFu + ((u >> 16) & 1u);           // round-to-nearest-even
    return (unsigned short)(u >> 16);
}
__device__ __forceinline__ float bf2f(unsigned short h) {
    unsigned u = ((unsigned)h) << 16;
    return __builtin_bit_cast(float, u);
}

// ---- pass 1: bin edges into bucket windows (edges cached in registers) -----
__global__ __launch_bounds__(256) void k_part(
    const int* __restrict__ src, const int* __restrict__ dst,
    int* __restrict__ gcur, int* __restrict__ pairs, int E) {
    __shared__ int hist[NBMAX];
    int tid = threadIdx.x;
    int e0  = blockIdx.x * CHUNK;
    int ds[CHUNK / 256], ss[CHUNK / 256];
#pragma unroll
    for (int j = 0; j < CHUNK / 256; j++) {
        int e = e0 + j * 256 + tid;
        if (e < E) { ds[j] = dst[e]; ss[j] = src[e]; } else ds[j] = -1;
    }
    for (int i = tid; i < NBMAX; i += 256) hist[i] = 0;
    __syncthreads();
#pragma unroll
    for (int j = 0; j < CHUNK / 256; j++)
        if (ds[j] >= 0) atomicAdd(&hist[ds[j] >> BSH], 1);
    __syncthreads();
    for (int i = tid; i < NBMAX; i += 256) {
        int c = hist[i];
        hist[i] = c ? atomicAdd(&gcur[i], c) : 0;
    }
    __syncthreads();
#pragma unroll
    for (int j = 0; j < CHUNK / 256; j++) {
        if (ds[j] >= 0) {
            int b = ds[j] >> BSH;
            int pos = atomicAdd(&hist[b], 1);
            if (pos < BCAP) pairs[b * BCAP + pos] = (ss[j] << BSH) | (ds[j] & 255);
        }
    }
}

// ---- exclusive scan of bucket counts ---------------------------------------
__global__ __launch_bounds__(NBMAX) void k_bucketbase(
    const int* __restrict__ gcur, int* __restrict__ bbase,
    int* __restrict__ rowptr, int nbuck, int n, int E) {
    __shared__ int s[NBMAX];
    int t = threadIdx.x;
    int v = (t < nbuck) ? gcur[t] : 0;
    s[t] = v;
    __syncthreads();
    for (int off = 1; off < NBMAX; off <<= 1) {
        int val = s[t];
        int add = (t >= off) ? s[t - off] : 0;
        __syncthreads();
        s[t] = val + add;
        __syncthreads();
    }
    if (t < nbuck) bbase[t] = s[t] - v;
    if (t == 0) rowptr[n] = E;
}

// ---- pass 2: per-bucket CSR build in LDS, coalesced stream-out -------------
__global__ __launch_bounds__(256) void k_build(
    const int* __restrict__ gcur, const int* __restrict__ bbase,
    const int* __restrict__ pairs, int* __restrict__ adj,
    int* __restrict__ rowptr, float* __restrict__ dinv, int n) {
    __shared__ int lcnt[256];
    __shared__ int lex[256];
    __shared__ int lcur[256];
    __shared__ int ladj[BCAP];
    int tid = threadIdx.x;
    int b   = blockIdx.x;
    int base  = bbase[b];
    int cntb  = gcur[b]; if (cntb > BCAP) cntb = BCAP;
    int node0 = b << BSH;
    const int* pb = pairs + (size_t)b * BCAP;

    lcnt[tid] = 0;
    __syncthreads();
    for (int k = tid; k < cntb; k += 256) atomicAdd(&lcnt[pb[k] & 255], 1);
    __syncthreads();
    int own = lcnt[tid];
    lex[tid] = own;
    __syncthreads();
    for (int off = 1; off < 256; off <<= 1) {
        int val = lex[tid];
        int add = (tid >= off) ? lex[tid - off] : 0;
        __syncthreads();
        lex[tid] = val + add;
        __syncthreads();
    }
    int excl = lex[tid] - own;
    __syncthreads();
    lex[tid]  = excl;
    lcur[tid] = excl;
    __syncthreads();
    for (int k = tid; k < cntb; k += 256) {
        int pk  = pb[k];
        int pos = atomicAdd(&lcur[pk & 255], 1);
        ladj[pos] = pk >> BSH;
    }
    __syncthreads();
    for (int k = tid; k < cntb; k += 256) adj[base + k] = ladj[k];
    int node = node0 + tid;
    if (node < n) {
        rowptr[node] = base + lex[tid];
        dinv[node]   = rsqrtf((float)own + 1.0f);
    }
}

// ---- layer 1 GEMM (tiled): hs1 = bf16( (x @ W1) * dinv ) -------------------
__global__ __launch_bounds__(256) void k_mm1(
    const float* __restrict__ x, const float* __restrict__ W1,
    const float* __restrict__ dinv, unsigned short* __restrict__ hs, int n) {
    __shared__ float Ws[FIN * F1];   // 32 KB
    __shared__ float As[KC][MT];     // 8 KB
    int t  = threadIdx.x;
    int n0 = blockIdx.x * MT;
#pragma unroll
    for (int j = 0; j < 8; j++) {
        int f = j * 256 + t;
        ((float4*)Ws)[f] = ((const float4*)W1)[f];
    }
    int m0 = (t & 15) * 8;
    int c0 = (t >> 4) * 4;
    int m_l = t & 127;
    int kh  = (t >> 7) * 8;
    bool mvalid = (n0 + m_l) < n;
    const float* xrow = x + (size_t)(n0 + m_l) * FIN + kh;
    float acc[8][4] = {};
    for (int kc = 0; kc < FIN; kc += KC) {
        __syncthreads();
        float4 v0 = mvalid ? *(const float4*)(xrow + kc)     : float4{0.f,0.f,0.f,0.f};
        float4 v1 = mvalid ? *(const float4*)(xrow + kc + 4) : float4{0.f,0.f,0.f,0.f};
        As[kh + 0][m_l] = v0.x; As[kh + 1][m_l] = v0.y;
        As[kh + 2][m_l] = v0.z; As[kh + 3][m_l] = v0.w;
        As[kh + 4][m_l] = v1.x; As[kh + 5][m_l] = v1.y;
        As[kh + 6][m_l] = v1.z; As[kh + 7][m_l] = v1.w;
        __syncthreads();
#pragma unroll
        for (int k = 0; k < KC; k++) {
            float4 a0 = *(const float4*)&As[k][m0];
            float4 a1 = *(const float4*)&As[k][m0 + 4];
            float4 w  = *(const float4*)&Ws[(kc + k) * F1 + c0];
            float a[8] = {a0.x, a0.y, a0.z, a0.w, a1.x, a1.y, a1.z, a1.w};
#pragma unroll
            for (int i = 0; i < 8; i++) {
                acc[i][0] += a[i] * w.x;
                acc[i][1] += a[i] * w.y;
                acc[i][2] += a[i] * w.z;
                acc[i][3] += a[i] * w.w;
            }
        }
    }
#pragma unroll
    for (int i = 0; i < 8; i++) {
        int node = n0 + m0 + i;
        if (node < n) {
            float dv = dinv[node];
            ushort4 o = { f2bf(acc[i][0] * dv), f2bf(acc[i][1] * dv),
                          f2bf(acc[i][2] * dv), f2bf(acc[i][3] * dv) };
            *(ushort4*)&hs[(size_t)node * F1 + c0] = o;
        }
    }
}

// ---- layer 1 aggregate: h1 = relu(dinv*(gather+self) + b1) -----------------
// One wave per node. adj batch-loaded coalesced (lane i -> adj[beg+i]),
// src indices broadcast via __shfl, 8 independent gathers per step.
__global__ __launch_bounds__(256) void k_agg1(
    const int* __restrict__ rowptr, const int* __restrict__ adj,
    const unsigned short* __restrict__ hs, const float* __restrict__ dinv,
    const float* __restrict__ b1, float* __restrict__ h1, int n, int E) {
    int node = blockIdx.x * 4 + (threadIdx.x >> 6);
    if (node >= n) return;
    int lane = threadIdx.x & 63;
    int beg = rowptr[node], end = rowptr[node + 1];
    int deg = end - beg;
    float acc = bf2f(hs[(size_t)node * F1 + lane]);  // self-loop
    for (int base = 0; base < deg; base += 64) {
        int m = deg - base; if (m > 64) m = 64;
        int idx = beg + base + lane;
        int myadj = adj[idx < E ? idx : 0];          // coalesced batch load
        int e = 0;
        for (; e + 8 <= m; e += 8) {
            int s0 = __shfl(myadj, e + 0), s1 = __shfl(myadj, e + 1);
            int s2 = __shfl(myadj, e + 2), s3 = __shfl(myadj, e + 3);
            int s4 = __shfl(myadj, e + 4), s5 = __shfl(myadj, e + 5);
            int s6 = __shfl(myadj, e + 6), s7 = __shfl(myadj, e + 7);
            float a0 = bf2f(hs[(size_t)s0 * F1 + lane]);
            float a1 = bf2f(hs[(size_t)s1 * F1 + lane]);
            float a2 = bf2f(hs[(size_t)s2 * F1 + lane]);
            float a3 = bf2f(hs[(size_t)s3 * F1 + lane]);
            float a4 = bf2f(hs[(size_t)s4 * F1 + lane]);
            float a5 = bf2f(hs[(size_t)s5 * F1 + lane]);
            float a6 = bf2f(hs[(size_t)s6 * F1 + lane]);
            float a7 = bf2f(hs[(size_t)s7 * F1 + lane]);
            acc += ((a0 + a1) + (a2 + a3)) + ((a4 + a5) + (a6 + a7));
        }
        for (; e < m; e++) {
            int s = __shfl(myadj, e);
            acc += bf2f(hs[(size_t)s * F1 + lane]);
        }
    }
    float v = acc * dinv[node] + b1[lane];
    h1[(size_t)node * F1 + lane] = v > 0.f ? v : 0.f;
}

// ---- layer 2 GEMM (tiled): hs2 = bf16( (h1 @ W2) * dinv ), stride F2P ------
__global__ __launch_bounds__(256) void k_mm2(
    const float* __restrict__ h1, const float* __restrict__ W2,
    const float* __restrict__ dinv, unsigned short* __restrict__ hs2, int n) {
    __shared__ float Ws[F1 * F2P];   // 12 KB padded (cols 41..47 = 0)
    __shared__ float As[KC][MT];
    int t  = threadIdx.x;
    int n0 = blockIdx.x * MT;
    for (int idx = t; idx < F1 * F2P; idx += 256) {
        int k = idx / F2P, c = idx - k * F2P;
        Ws[idx] = (c < F2) ? W2[k * F2 + c] : 0.f;
    }
    int m0 = (t & 15) * 8;
    int c0 = (t >> 4) * 4;
    bool compute = (t < 192);        // waves 0-2 compute (48 cols), wave 3 stages
    int m_l = t & 127;
    int kh  = (t >> 7) * 8;
    bool mvalid = (n0 + m_l) < n;
    const float* hrow = h1 + (size_t)(n0 + m_l) * F1 + kh;
    float acc[8][4] = {};
    for (int kc = 0; kc < F1; kc += KC) {
        __syncthreads();
        float4 v0 = mvalid ? *(const float4*)(hrow + kc)     : float4{0.f,0.f,0.f,0.f};
        float4 v1 = mvalid ? *(const float4*)(hrow + kc + 4) : float4{0.f,0.f,0.f,0.f};
        As[kh + 0][m_l] = v0.x; As[kh + 1][m_l] = v0.y;
        As[kh + 2][m_l] = v0.z; As[kh + 3][m_l] = v0.w;
        As[kh + 4][m_l] = v1.x; As[kh + 5][m_l] = v1.y;
        As[kh + 6][m_l] = v1.z; As[kh + 7][m_l] = v1.w;
        __syncthreads();
        if (compute) {
#pragma unroll
            for (int k = 0; k < KC; k++) {
                float4 a0 = *(const float4*)&As[k][m0];
                float4 a1 = *(const float4*)&As[k][m0 + 4];
                float4 w  = *(const float4*)&Ws[(kc + k) * F2P + c0];
                float a[8] = {a0.x, a0.y, a0.z, a0.w, a1.x, a1.y, a1.z, a1.w};
#pragma unroll
                for (int i = 0; i < 8; i++) {
                    acc[i][0] += a[i] * w.x;
                    acc[i][1] += a[i] * w.y;
                    acc[i][2] += a[i] * w.z;
                    acc[i][3] += a[i] * w.w;
                }
            }
        }
    }
    if (compute) {
#pragma unroll
        for (int i = 0; i < 8; i++) {
            int node = n0 + m0 + i;
            if (node < n) {
                float dv = dinv[node];
                ushort4 o = { f2bf(acc[i][0] * dv), f2bf(acc[i][1] * dv),
                              f2bf(acc[i][2] * dv), f2bf(acc[i][3] * dv) };
                *(ushort4*)&hs2[(size_t)node * F2P + c0] = o;
            }
        }
    }
}

// ---- layer 2 aggregate: out = dinv*(gather+self) + b2 ----------------------
// Same MLP structure; lanes >= F2 clamp to feature 0 (valid addr, discarded).
__global__ __launch_bounds__(256) void k_agg2(
    const int* __restrict__ rowptr, const int* __restrict__ adj,
    const unsigned short* __restrict__ hs2, const float* __restrict__ dinv,
    const float* __restrict__ b2, float* __restrict__ out, int n, int E) {
    int node = blockIdx.x * 4 + (threadIdx.x >> 6);
    if (node >= n) return;
    int lane = threadIdx.x & 63;
    int fl   = (lane < F2) ? lane : 0;   // branch-free: clamped feature index
    int beg = rowptr[node], end = rowptr[node + 1];
    int deg = end - beg;
    float acc = bf2f(hs2[(size_t)node * F2P + fl]);  // self-loop
    for (int base = 0; base < deg; base += 64) {
        int m = deg - base; if (m > 64) m = 64;
        int idx = beg + base + lane;
        int myadj = adj[idx < E ? idx : 0];          // coalesced batch load
        int e = 0;
        for (; e + 8 <= m; e += 8) {
            int s0 = __shfl(myadj, e + 0), s1 = __shfl(myadj, e + 1);
            int s2 = __shfl(myadj, e + 2), s3 = __shfl(myadj, e + 3);
            int s4 = __shfl(myadj, e + 4), s5 = __shfl(myadj, e + 5);
            int s6 = __shfl(myadj, e + 6), s7 = __shfl(myadj, e + 7);
            float a0 = bf2f(hs2[(size_t)s0 * F2P + fl]);
            float a1 = bf2f(hs2[(size_t)s1 * F2P + fl]);
            float a2 = bf2f(hs2[(size_t)s2 * F2P + fl]);
            float a3 = bf2f(hs2[(size_t)s3 * F2P + fl]);
            float a4 = bf2f(hs2[(size_t)s4 * F2P + fl]);
            float a5 = bf2f(hs2[(size_t)s5 * F2P + fl]);
            float a6 = bf2f(hs2[(size_t)s6 * F2P + fl]);
            float a7 = bf2f(hs2[(size_t)s7 * F2P + fl]);
            acc += ((a0 + a1) + (a2 + a3)) + ((a4 + a5) + (a6 + a7));
        }
        for (; e < m; e++) {
            int s = __shfl(myadj, e);
            acc += bf2f(hs2[(size_t)s * F2P + fl]);
        }
    }
    if (lane < F2) out[(size_t)node * F2 + lane] = acc * dinv[node] + b2[lane];
}

__global__ void k_zero(int* __restrict__ p, int n) {
    int i = blockIdx.x * blockDim.x + threadIdx.x;
    if (i < n) p[i] = 0;
}

extern "C" void kernel_launch(void* const* d_in, const int* in_sizes, int n_in,
                              void* d_out, int out_size, void* d_ws, size_t ws_size,
                              hipStream_t stream) {
    const float* x  = (const float*)d_in[0];
    const int*   ei = (const int*)d_in[1];
    const float* W1 = (const float*)d_in[2];
    const float* b1 = (const float*)d_in[3];
    const float* W2 = (const float*)d_in[4];
    const float* b2 = (const float*)d_in[5];
    float* out = (float*)d_out;

    const int n = in_sizes[0] / FIN;   // 100000
    const int E = in_sizes[1] / 2;     // 1600000
    const int* src = ei;
    const int* dst = ei + E;
    const int nbuck   = (n + 255) >> BSH;           // 391 (<= NBMAX)
    const int nchunks = (E + CHUNK - 1) / CHUNK;    // 391
    const int nmm     = (n + MT - 1) / MT;          // 782

    char* ws = (char*)d_ws;
    size_t off = 0;
    auto alloc = [&](size_t bytes) {
        void* p = ws + off;
        off = (off + bytes + 511) & ~(size_t)511;
        return p;
    };
    int*   gcur   = (int*)alloc((size_t)NBMAX * 4);
    int*   bbase  = (int*)alloc((size_t)NBMAX * 4);
    int*   pairs  = (int*)alloc((size_t)nbuck * BCAP * 4);   // ~9.6 MB
    int*   adj    = (int*)alloc((size_t)E * 4);
    int*   rowptr = (int*)alloc((size_t)(n + 1) * 4);
    float* dinv   = (float*)alloc((size_t)n * 4);
    unsigned short* bufHS = (unsigned short*)alloc((size_t)n * F1 * 2); // hs1 bf16; later hs2
    float* bufH1  = (float*)alloc((size_t)n * F1 * 4);   // h1 fp32

    // ---- CSR build ----
    k_zero<<<(NBMAX + 255) / 256, 256, 0, stream>>>(gcur, NBMAX);
    k_part<<<nchunks, 256, 0, stream>>>(src, dst, gcur, pairs, E);
    k_bucketbase<<<1, NBMAX, 0, stream>>>(gcur, bbase, rowptr, nbuck, n, E);
    k_build<<<nbuck, 256, 0, stream>>>(gcur, bbase, pairs, adj, rowptr, dinv, n);

    // ---- layer 1 ----
    k_mm1<<<nmm, 256, 0, stream>>>(x, W1, dinv, bufHS, n);
    k_agg1<<<(n + 3) / 4, 256, 0, stream>>>(rowptr, adj, bufHS, dinv, b1, bufH1, n, E);

    // ---- layer 2 ----
    k_mm2<<<nmm, 256, 0, stream>>>(bufH1, W2, dinv, bufHS, n);
    k_agg2<<<(n + 3) / 4, 256, 0, stream>>>(rowptr, adj, bufHS, dinv, b2, out, n, E);
}